// Round 13
// baseline (752.960 us; speedup 1.0000x reference)
//
#include <hip/hip_runtime.h>

#define NN 50000
#define EE 800000
#define ET 850000   // EE + NN self loops
#define HH 4
#define CC 64
#define FDIM 256    // HH*CC

#define SCAN_BLK 512
#define SCAN_NB ((NN + SCAN_BLK - 1) / SCAN_BLK)   // 98

typedef unsigned short ushort;
typedef __bf16 bf16x8 __attribute__((ext_vector_type(8)));
typedef float floatx4 __attribute__((ext_vector_type(4)));
typedef ushort ushort8v __attribute__((ext_vector_type(8)));
struct ushort4s { ushort x, y, z, w; };

__device__ __forceinline__ ushort f2bf(float f) {
  union { float f; unsigned u; } v; v.f = f;
  unsigned r = v.u + 0x7fffu + ((v.u >> 16) & 1u);  // RNE
  return (ushort)(r >> 16);
}
__device__ __forceinline__ float bf2f(ushort u) {
  return __uint_as_float(((unsigned)u) << 16);
}

// ---------- edge-index dtype handling (int32 vs int64 at runtime) ----------
__device__ __forceinline__ int get_edge(const void* p, int is64, long long idx) {
  if (is64) return (int)((const long long*)p)[idx];
  return ((const int*)p)[idx];
}

__global__ void detect_kernel(const unsigned int* p, int* flag) {
  // int64 with values < 50000 => every odd 32-bit word is 0
  __shared__ unsigned red[256];
  int t = threadIdx.x;
  unsigned o = 0;
  for (int i = 0; i < 4; i++) o |= p[(t * 4 + i) * 2 + 1];
  red[t] = o;
  __syncthreads();
  for (int s = 128; s > 0; s >>= 1) {
    if (t < s) red[t] |= red[t + s];
    __syncthreads();
  }
  if (t == 0) *flag = (red[0] == 0) ? 1 : 0;
}

// ---------- CSR build over dst ----------
__global__ void degree_kernel(const void* eidx, const int* flag, int* deg) {
  int k = blockIdx.x * blockDim.x + threadIdx.x;
  if (k >= ET) return;
  int is64 = *flag;
  int dst = (k < EE) ? get_edge(eidx, is64, (long long)EE + k) : (k - EE);
  atomicAdd(&deg[dst], 1);
}

__global__ __launch_bounds__(SCAN_BLK) void scan1_kernel(const int* __restrict__ deg,
                                                         int* __restrict__ rowptr,
                                                         int* __restrict__ bsum) {
  __shared__ int sm[SCAN_BLK];
  int t = threadIdx.x;
  int i = blockIdx.x * SCAN_BLK + t;
  int v = (i < NN) ? deg[i] : 0;
  sm[t] = v;
  __syncthreads();
#pragma unroll
  for (int o = 1; o < SCAN_BLK; o <<= 1) {
    int u = (t >= o) ? sm[t - o] : 0;
    __syncthreads();
    sm[t] += u;
    __syncthreads();
  }
  if (i < NN) rowptr[i] = sm[t] - v;                 // local exclusive
  if (t == SCAN_BLK - 1) bsum[blockIdx.x] = sm[t];   // block total
}

__global__ __launch_bounds__(128) void scan2_kernel(const int* __restrict__ bsum,
                                                    int* __restrict__ boff,
                                                    int* __restrict__ rowptr) {
  __shared__ int sm[128];
  int t = threadIdx.x;
  int v = (t < SCAN_NB) ? bsum[t] : 0;
  sm[t] = v;
  __syncthreads();
#pragma unroll
  for (int o = 1; o < 128; o <<= 1) {
    int u = (t >= o) ? sm[t - o] : 0;
    __syncthreads();
    sm[t] += u;
    __syncthreads();
  }
  if (t < SCAN_NB) boff[t] = sm[t] - v;  // exclusive block offset
  if (t == 0) rowptr[NN] = ET;
}

__global__ __launch_bounds__(SCAN_BLK) void scan3_kernel(int* __restrict__ rowptr,
                                                         int* __restrict__ cursor,
                                                         const int* __restrict__ boff) {
  int i = blockIdx.x * SCAN_BLK + threadIdx.x;
  if (i >= NN) return;
  int v = rowptr[i] + boff[blockIdx.x];
  rowptr[i] = v;
  cursor[i] = v;
}

__global__ void fill_kernel(const void* eidx, const int* flag, int* cursor, int* csr_src) {
  int k = blockIdx.x * blockDim.x + threadIdx.x;
  if (k >= ET) return;
  int is64 = *flag;
  int src, dst;
  if (k < EE) {
    src = get_edge(eidx, is64, k);
    dst = get_edge(eidx, is64, (long long)EE + k);
  } else {
    src = dst = k - EE;
  }
  int pos = atomicAdd(&cursor[dst], 1);
  csr_src[pos] = src;
}

// ---------- weight transpose via LDS tiles (coalesced reads AND writes) ----------
// grid: (4, 4, 3) -> 64x64 tile (bi*64 rows of W, bj*64 cols), matrix z.
__global__ __launch_bounds__(256) void conv_w_kernel(const float* __restrict__ W0,
                                                     const float* __restrict__ W1,
                                                     const float* __restrict__ W2,
                                                     ushort* __restrict__ T0,
                                                     ushort* __restrict__ T1,
                                                     ushort* __restrict__ T2) {
  __shared__ float tile[64][65];
  const float* W = (blockIdx.z == 0) ? W0 : (blockIdx.z == 1) ? W1 : W2;
  ushort* Wt = (blockIdx.z == 0) ? T0 : (blockIdx.z == 1) ? T1 : T2;
  int bi = blockIdx.x * 64;   // k-base
  int bj = blockIdx.y * 64;   // n-base
  int tn = threadIdx.x & 63;
  int tr = threadIdx.x >> 6;
  for (int r = tr; r < 64; r += 4)
    tile[r][tn] = W[(size_t)(bi + r) * 256 + bj + tn];
  __syncthreads();
  for (int r = tr; r < 64; r += 4)
    Wt[(size_t)(bj + r) * 256 + bi + tn] = f2bf(tile[tn][r]);
}

// ---------- bf16 MFMA GEMM: B register-resident, barrier-free row loop ----------
// C[M,256] = A[M,256] @ B[256,256] (B given transposed as Bt[n][k]).
// grid (256, 2), block 256 = 4 waves, __launch_bounds__(256,2) -> 2 blocks/CU.
// Wave w owns head = blockIdx.y*2 + (w&1): cols col0..col0+64. Its 64x256
// B-slice = 32 fragments x 16 B = 128 VGPRs, loaded ONCE (L2-hot).
// Row loop (grid-stride, 32 rows/block-iter; wave handles 16 rows): 8
// independent 16-B A-loads + 32 MFMAs. No LDS traffic, no barriers ->
// iterations pipeline freely (this was the blocker in every prior variant:
// LDS versions drain vmcnt at 16 barriers/block; LDS-free re-loaded B 48x).
// MODE 0: A f32 (layer 0). MODE 1: A bf16 agg output, GraphNorm+LeakyReLU
// fused into the A-load (sc/sh in LDS, loop-invariant).
// Epilogue per row-tile: C store + s/d plain stores (each (row,head) once).
template <int MODE>
__global__ __launch_bounds__(256, 2) void gemm_bf16(const void* __restrict__ Ap,
                                                    const ushort* __restrict__ Bt,
                                                    ushort* __restrict__ C,
                                                    const float* __restrict__ as_,
                                                    const float* __restrict__ ad_,
                                                    float* __restrict__ s_arr,
                                                    float* __restrict__ d_arr,
                                                    const float* __restrict__ colsum,
                                                    const float* __restrict__ colsumsq,
                                                    const float* __restrict__ ga,
                                                    const float* __restrict__ gw,
                                                    const float* __restrict__ gb) {
  __shared__ float scs[FDIM], shs[FDIM];
  int tid = threadIdx.x, w = tid >> 6, l = tid & 63;
  int lm = l & 15, lk = (l >> 4) * 8;
  int col0 = blockIdx.y * 128 + (w & 1) * 64;
  int head = blockIdx.y * 2 + (w & 1);
  int rowofs = (w >> 1) * 16;
  int quad = l >> 4;

  if constexpr (MODE == 1) {
    const float invn = 1.0f / (float)NN;
    float mu = colsum[tid] * invn;
    float ex2 = colsumsq[tid] * invn;
    float a = ga[tid];
    float var = fmaxf(ex2 - (2.f * a - a * a) * mu * mu, 0.f);
    float s = gw[tid] * rsqrtf(var + 1e-5f);
    scs[tid] = s;
    shs[tid] = gb[tid] - s * a * mu;
    __syncthreads();
  }

  // B-fragments: 4 col-subtiles x 8 k-blocks, register-resident (128 VGPR)
  bf16x8 bfr[4][8];
#pragma unroll
  for (int s = 0; s < 4; s++) {
    const ushort* bp = Bt + (size_t)(col0 + s * 16 + lm) * 256 + lk;
#pragma unroll
    for (int kb = 0; kb < 8; kb++)
      bfr[s][kb] = *(const bf16x8*)(bp + kb * 32);
  }

  float asv[4], adv[4];
#pragma unroll
  for (int s = 0; s < 4; s++) {
    asv[s] = as_[col0 + s * 16 + lm];
    adv[s] = ad_[col0 + s * 16 + lm];
  }

  for (int rt = blockIdx.x * 32; rt < NN; rt += gridDim.x * 32) {
    int row0 = rt + rowofs;                  // 16 rows: row0 .. row0+15
    int arow = min(row0 + lm, NN - 1);
    bf16x8 afr[8];
    if constexpr (MODE == 0) {
      const float* ap = (const float*)Ap + (size_t)arow * 256 + lk;
#pragma unroll
      for (int kb = 0; kb < 8; kb++) {
        float4 u = *(const float4*)(ap + kb * 32);
        float4 v = *(const float4*)(ap + kb * 32 + 4);
        ushort8v t = ushort8v{f2bf(u.x), f2bf(u.y), f2bf(u.z), f2bf(u.w),
                              f2bf(v.x), f2bf(v.y), f2bf(v.z), f2bf(v.w)};
        afr[kb] = *(bf16x8*)&t;
      }
    } else {
      const ushort* ap = (const ushort*)Ap + (size_t)arow * 256 + lk;
#pragma unroll
      for (int kb = 0; kb < 8; kb++) {
        ushort8v r = *(const ushort8v*)(ap + kb * 32);
        ushort8v t;
        int kbase = kb * 32 + lk;
#pragma unroll
        for (int j = 0; j < 8; j++) {
          float y = fmaf(scs[kbase + j], bf2f(r[j]), shs[kbase + j]);
          y = fmaxf(y, 0.01f * y);   // LeakyReLU(0.01)
          t[j] = f2bf(y);
        }
        afr[kb] = *(bf16x8*)&t;
      }
    }
    floatx4 acc[4];
#pragma unroll
    for (int s = 0; s < 4; s++) acc[s] = floatx4{0.f, 0.f, 0.f, 0.f};
#pragma unroll
    for (int kb = 0; kb < 8; kb++)
#pragma unroll
      for (int s = 0; s < 4; s++)
        acc[s] = __builtin_amdgcn_mfma_f32_16x16x32_bf16(afr[kb], bfr[s][kb], acc[s], 0, 0, 0);

    // ----- C store -----
#pragma unroll
    for (int s = 0; s < 4; s++) {
      int col = col0 + s * 16 + lm;
#pragma unroll
      for (int r = 0; r < 4; r++) {
        int row = row0 + quad * 4 + r;
        if (row < NN) C[(size_t)row * 256 + col] = f2bf(acc[s][r]);
      }
    }
    // ----- s/d epilogue -----
#pragma unroll
    for (int r = 0; r < 4; r++) {
      float sp = acc[0][r] * asv[0] + acc[1][r] * asv[1] +
                 acc[2][r] * asv[2] + acc[3][r] * asv[3];
      float dp = acc[0][r] * adv[0] + acc[1][r] * adv[1] +
                 acc[2][r] * adv[2] + acc[3][r] * adv[3];
      sp += __shfl_xor(sp, 1); dp += __shfl_xor(dp, 1);
      sp += __shfl_xor(sp, 2); dp += __shfl_xor(dp, 2);
      sp += __shfl_xor(sp, 4); dp += __shfl_xor(dp, 4);
      sp += __shfl_xor(sp, 8); dp += __shfl_xor(dp, 8);
      if (lm == 0) {
        int row = row0 + quad * 4 + r;
        if (row < NN) {
          s_arr[row * HH + head] = sp;
          d_arr[row * HH + head] = dp;
        }
      }
    }
  }
}

// ---------- aggregation: one wave per node, all heads; fused edge softmax ----------
template <bool CONCAT>
__global__ __launch_bounds__(256) void agg_kernel(const ushort* __restrict__ hb,
                                                  const float* __restrict__ s_arr,
                                                  const float* __restrict__ d_arr,
                                                  const int* __restrict__ rowptr,
                                                  const int* __restrict__ csr_src,
                                                  const float* __restrict__ bias,
                                                  void* __restrict__ outp) {
  int w = __builtin_amdgcn_readfirstlane(threadIdx.x >> 6);
  int l = threadIdx.x & 63;
  int head = l >> 4;
  int n = blockIdx.x * 4 + w;
  int beg = rowptr[n], end = rowptr[n + 1];
  float dh = d_arr[n * HH + head];
  float a0 = 0.f, a1 = 0.f, a2 = 0.f, a3 = 0.f, den = 0.f;

  int i = beg;
  for (; i + 8 <= end; i += 8) {
    int s0 = csr_src[i], s1 = csr_src[i + 1], s2 = csr_src[i + 2], s3 = csr_src[i + 3];
    int s4 = csr_src[i + 4], s5 = csr_src[i + 5], s6 = csr_src[i + 6], s7 = csr_src[i + 7];
    float e0 = s_arr[s0 * HH + head] + dh;
    float e1 = s_arr[s1 * HH + head] + dh;
    float e2 = s_arr[s2 * HH + head] + dh;
    float e3 = s_arr[s3 * HH + head] + dh;
    float e4 = s_arr[s4 * HH + head] + dh;
    float e5 = s_arr[s5 * HH + head] + dh;
    float e6 = s_arr[s6 * HH + head] + dh;
    float e7 = s_arr[s7 * HH + head] + dh;
    ushort4s h0 = *(const ushort4s*)(hb + (unsigned)(s0 * FDIM + l * 4));
    ushort4s h1 = *(const ushort4s*)(hb + (unsigned)(s1 * FDIM + l * 4));
    ushort4s h2 = *(const ushort4s*)(hb + (unsigned)(s2 * FDIM + l * 4));
    ushort4s h3 = *(const ushort4s*)(hb + (unsigned)(s3 * FDIM + l * 4));
    ushort4s h4 = *(const ushort4s*)(hb + (unsigned)(s4 * FDIM + l * 4));
    ushort4s h5 = *(const ushort4s*)(hb + (unsigned)(s5 * FDIM + l * 4));
    ushort4s h6 = *(const ushort4s*)(hb + (unsigned)(s6 * FDIM + l * 4));
    ushort4s h7 = *(const ushort4s*)(hb + (unsigned)(s7 * FDIM + l * 4));
    e0 = (e0 > 0.f) ? e0 : 0.2f * e0;  float w0 = __expf(e0);
    e1 = (e1 > 0.f) ? e1 : 0.2f * e1;  float w1 = __expf(e1);
    e2 = (e2 > 0.f) ? e2 : 0.2f * e2;  float w2 = __expf(e2);
    e3 = (e3 > 0.f) ? e3 : 0.2f * e3;  float w3 = __expf(e3);
    e4 = (e4 > 0.f) ? e4 : 0.2f * e4;  float w4 = __expf(e4);
    e5 = (e5 > 0.f) ? e5 : 0.2f * e5;  float w5 = __expf(e5);
    e6 = (e6 > 0.f) ? e6 : 0.2f * e6;  float w6 = __expf(e6);
    e7 = (e7 > 0.f) ? e7 : 0.2f * e7;  float w7 = __expf(e7);
    den += ((w0 + w1) + (w2 + w3)) + ((w4 + w5) + (w6 + w7));
    a0 = fmaf(w0, bf2f(h0.x), a0); a1 = fmaf(w0, bf2f(h0.y), a1);
    a2 = fmaf(w0, bf2f(h0.z), a2); a3 = fmaf(w0, bf2f(h0.w), a3);
    a0 = fmaf(w1, bf2f(h1.x), a0); a1 = fmaf(w1, bf2f(h1.y), a1);
    a2 = fmaf(w1, bf2f(h1.z), a2); a3 = fmaf(w1, bf2f(h1.w), a3);
    a0 = fmaf(w2, bf2f(h2.x), a0); a1 = fmaf(w2, bf2f(h2.y), a1);
    a2 = fmaf(w2, bf2f(h2.z), a2); a3 = fmaf(w2, bf2f(h2.w), a3);
    a0 = fmaf(w3, bf2f(h3.x), a0); a1 = fmaf(w3, bf2f(h3.y), a1);
    a2 = fmaf(w3, bf2f(h3.z), a2); a3 = fmaf(w3, bf2f(h3.w), a3);
    a0 = fmaf(w4, bf2f(h4.x), a0); a1 = fmaf(w4, bf2f(h4.y), a1);
    a2 = fmaf(w4, bf2f(h4.z), a2); a3 = fmaf(w4, bf2f(h4.w), a3);
    a0 = fmaf(w5, bf2f(h5.x), a0); a1 = fmaf(w5, bf2f(h5.y), a1);
    a2 = fmaf(w5, bf2f(h5.z), a2); a3 = fmaf(w5, bf2f(h5.w), a3);
    a0 = fmaf(w6, bf2f(h6.x), a0); a1 = fmaf(w6, bf2f(h6.y), a1);
    a2 = fmaf(w6, bf2f(h6.z), a2); a3 = fmaf(w6, bf2f(h6.w), a3);
    a0 = fmaf(w7, bf2f(h7.x), a0); a1 = fmaf(w7, bf2f(h7.y), a1);
    a2 = fmaf(w7, bf2f(h7.z), a2); a3 = fmaf(w7, bf2f(h7.w), a3);
  }
  for (; i + 4 <= end; i += 4) {
    int s0 = csr_src[i], s1 = csr_src[i + 1], s2 = csr_src[i + 2], s3 = csr_src[i + 3];
    float e0 = s_arr[s0 * HH + head] + dh;
    float e1 = s_arr[s1 * HH + head] + dh;
    float e2 = s_arr[s2 * HH + head] + dh;
    float e3 = s_arr[s3 * HH + head] + dh;
    ushort4s h0 = *(const ushort4s*)(hb + (unsigned)(s0 * FDIM + l * 4));
    ushort4s h1 = *(const ushort4s*)(hb + (unsigned)(s1 * FDIM + l * 4));
    ushort4s h2 = *(const ushort4s*)(hb + (unsigned)(s2 * FDIM + l * 4));
    ushort4s h3 = *(const ushort4s*)(hb + (unsigned)(s3 * FDIM + l * 4));
    e0 = (e0 > 0.f) ? e0 : 0.2f * e0;  float w0 = __expf(e0);
    e1 = (e1 > 0.f) ? e1 : 0.2f * e1;  float w1 = __expf(e1);
    e2 = (e2 > 0.f) ? e2 : 0.2f * e2;  float w2 = __expf(e2);
    e3 = (e3 > 0.f) ? e3 : 0.2f * e3;  float w3 = __expf(e3);
    den += (w0 + w1) + (w2 + w3);
    a0 = fmaf(w0, bf2f(h0.x), a0); a1 = fmaf(w0, bf2f(h0.y), a1);
    a2 = fmaf(w0, bf2f(h0.z), a2); a3 = fmaf(w0, bf2f(h0.w), a3);
    a0 = fmaf(w1, bf2f(h1.x), a0); a1 = fmaf(w1, bf2f(h1.y), a1);
    a2 = fmaf(w1, bf2f(h1.z), a2); a3 = fmaf(w1, bf2f(h1.w), a3);
    a0 = fmaf(w2, bf2f(h2.x), a0); a1 = fmaf(w2, bf2f(h2.y), a1);
    a2 = fmaf(w2, bf2f(h2.z), a2); a3 = fmaf(w2, bf2f(h2.w), a3);
    a0 = fmaf(w3, bf2f(h3.x), a0); a1 = fmaf(w3, bf2f(h3.y), a1);
    a2 = fmaf(w3, bf2f(h3.z), a2); a3 = fmaf(w3, bf2f(h3.w), a3);
  }
  for (; i < end; i++) {
    int s0 = csr_src[i];
    float e0 = s_arr[s0 * HH + head] + dh;
    ushort4s h0 = *(const ushort4s*)(hb + (unsigned)(s0 * FDIM + l * 4));
    e0 = (e0 > 0.f) ? e0 : 0.2f * e0;
    float w0 = __expf(e0);
    den += w0;
    a0 = fmaf(w0, bf2f(h0.x), a0); a1 = fmaf(w0, bf2f(h0.y), a1);
    a2 = fmaf(w0, bf2f(h0.z), a2); a3 = fmaf(w0, bf2f(h0.w), a3);
  }
  float inv = 1.0f / den;  // self loop guarantees den > 0
  float r0 = a0 * inv, r1 = a1 * inv, r2 = a2 * inv, r3 = a3 * inv;

  if (CONCAT) {
    float4 bv = ((const float4*)bias)[l];
    ushort4s o;
    o.x = f2bf(r0 + bv.x); o.y = f2bf(r1 + bv.y);
    o.z = f2bf(r2 + bv.z); o.w = f2bf(r3 + bv.w);
    ((ushort4s*)outp)[(unsigned)(n * 64 + l)] = o;
  } else {
    r0 += __shfl_xor(r0, 16); r1 += __shfl_xor(r1, 16);
    r2 += __shfl_xor(r2, 16); r3 += __shfl_xor(r3, 16);
    r0 += __shfl_xor(r0, 32); r1 += __shfl_xor(r1, 32);
    r2 += __shfl_xor(r2, 32); r3 += __shfl_xor(r3, 32);
    if (l < 16) {
      float4 bv = ((const float4*)bias)[l];
      float4 o;
      o.x = 0.25f * r0 + bv.x; o.y = 0.25f * r1 + bv.y;
      o.z = 0.25f * r2 + bv.z; o.w = 0.25f * r3 + bv.w;
      ((float4*)outp)[(unsigned)(n * 16 + l)] = o;
    }
  }
}

// ---------- GraphNorm reduce ----------
__global__ __launch_bounds__(256) void norm_reduce_bf(const ushort* __restrict__ xin,
                                                      float* colsum, float* colsumsq) {
  __shared__ float4 sm1[256], sm2[256];
  int t = threadIdx.x;
  int c4 = (t & 63) * 4;
  int rl = t >> 6;
  int r0 = blockIdx.x * 128;
  int r1 = min(NN, r0 + 128);
  float s0 = 0.f, s1 = 0.f, s2 = 0.f, s3 = 0.f;
  float q0 = 0.f, q1 = 0.f, q2 = 0.f, q3 = 0.f;
  for (int r = r0 + rl; r < r1; r += 4) {
    ushort4s v = *(const ushort4s*)(xin + (size_t)r * FDIM + c4);
    float f0 = bf2f(v.x), f1 = bf2f(v.y), f2 = bf2f(v.z), f3 = bf2f(v.w);
    s0 += f0; q0 += f0 * f0;
    s1 += f1; q1 += f1 * f1;
    s2 += f2; q2 += f2 * f2;
    s3 += f3; q3 += f3 * f3;
  }
  sm1[t] = float4{s0, s1, s2, s3};
  sm2[t] = float4{q0, q1, q2, q3};
  __syncthreads();
  if (t < 64) {
    float4 a = sm1[t], b = sm1[t + 64], c = sm1[t + 128], d = sm1[t + 192];
    atomicAdd(&colsum[c4 + 0], a.x + b.x + c.x + d.x);
    atomicAdd(&colsum[c4 + 1], a.y + b.y + c.y + d.y);
    atomicAdd(&colsum[c4 + 2], a.z + b.z + c.z + d.z);
    atomicAdd(&colsum[c4 + 3], a.w + b.w + c.w + d.w);
    float4 e = sm2[t], f = sm2[t + 64], g = sm2[t + 128], h = sm2[t + 192];
    atomicAdd(&colsumsq[c4 + 0], e.x + f.x + g.x + h.x);
    atomicAdd(&colsumsq[c4 + 1], e.y + f.y + g.y + h.y);
    atomicAdd(&colsumsq[c4 + 2], e.z + f.z + g.z + h.z);
    atomicAdd(&colsumsq[c4 + 3], e.w + f.w + g.w + h.w);
  }
}

__global__ __launch_bounds__(256) void norm_reduce_f32(const float* __restrict__ xin,
                                                       float* colsum, float* colsumsq) {
  int f = threadIdx.x & (CC - 1);
  int rl = threadIdx.x / CC;
  int r0 = blockIdx.x * 128;
  int r1 = min(NN, r0 + 128);
  float s1 = 0.f, s2 = 0.f;
  for (int r = r0 + rl; r < r1; r += 4) {
    float v = xin[(size_t)r * CC + f];
    s1 += v; s2 += v * v;
  }
  atomicAdd(&colsum[f], s1);
  atomicAdd(&colsumsq[f], s2);
}

// ---------- MLP 64->32->16->2 with fused GraphNorm+LeakyReLU on input ----------
__global__ __launch_bounds__(256) void mlp_kernel(const float* __restrict__ xin,
                                                  const float* __restrict__ colsum,
                                                  const float* __restrict__ colsumsq,
                                                  const float* __restrict__ ga,
                                                  const float* __restrict__ gw,
                                                  const float* __restrict__ gb,
                                                  const float* mW0, const float* mb0,
                                                  const float* mW1, const float* mb1,
                                                  const float* mW2, const float* mb2,
                                                  float* __restrict__ out) {
  __shared__ float W0s[64 * 32];
  __shared__ float W1s[32 * 16];
  __shared__ float W2s[16 * 2];
  __shared__ float b0s[32], b1s[16], b2s[2];
  __shared__ float sc[CC], sh[CC];
  int t = threadIdx.x;
  for (int i = t; i < 2048; i += 256) W0s[i] = mW0[i];
  for (int i = t; i < 512; i += 256) W1s[i] = mW1[i];
  if (t < 32) { W2s[t] = mW2[t]; b0s[t] = mb0[t]; }
  if (t < 16) b1s[t] = mb1[t];
  if (t < 2) b2s[t] = mb2[t];
  if (t < CC) {
    const float invn = 1.0f / (float)NN;
    float mu = colsum[t] * invn;
    float ex2 = colsumsq[t] * invn;
    float a = ga[t];
    float var = fmaxf(ex2 - (2.f * a - a * a) * mu * mu, 0.f);
    float s = gw[t] * rsqrtf(var + 1e-5f);
    sc[t] = s; sh[t] = gb[t] - s * a * mu;
  }
  __syncthreads();
  int node = blockIdx.x * 256 + t;
  if (node >= NN) return;
  float in[64];
  const float* xr = xin + (size_t)node * 64;
#pragma unroll
  for (int k = 0; k < 64; k++) {
    float y = sc[k] * xr[k] + sh[k];
    in[k] = (y > 0.f) ? y : 0.01f * y;   // GraphNorm + LeakyReLU(0.01) fused
  }
  float h1[32];
#pragma unroll
  for (int j = 0; j < 32; j++) h1[j] = b0s[j];
#pragma unroll
  for (int k = 0; k < 64; k++) {
    float v = in[k];
#pragma unroll
    for (int j = 0; j < 32; j++) h1[j] += v * W0s[k * 32 + j];
  }
#pragma unroll
  for (int j = 0; j < 32; j++) h1[j] = fmaxf(h1[j], 0.f);
  float h2[16];
#pragma unroll
  for (int j = 0; j < 16; j++) h2[j] = b1s[j];
#pragma unroll
  for (int k = 0; k < 32; k++) {
    float v = h1[k];
#pragma unroll
    for (int j = 0; j < 16; j++) h2[j] += v * W1s[k * 16 + j];
  }
#pragma unroll
  for (int j = 0; j < 16; j++) h2[j] = fmaxf(h2[j], 0.f);
  float o0 = b2s[0], o1 = b2s[1];
#pragma unroll
  for (int k = 0; k < 16; k++) {
    o0 += h2[k] * W2s[k * 2 + 0];
    o1 += h2[k] * W2s[k * 2 + 1];
  }
  out[(size_t)node * 2 + 0] = o0;
  out[(size_t)node * 2 + 1] = o1;
}

extern "C" void kernel_launch(void* const* d_in, const int* in_sizes, int n_in,
                              void* d_out, int out_size, void* d_ws, size_t ws_size,
                              hipStream_t stream) {
  const float* x = (const float*)d_in[0];
  const void* ei = d_in[1];
  const float* W[3]   = {(const float*)d_in[2],  (const float*)d_in[9],  (const float*)d_in[16]};
  const float* as_[3] = {(const float*)d_in[3],  (const float*)d_in[10], (const float*)d_in[17]};
  const float* ad_[3] = {(const float*)d_in[4],  (const float*)d_in[11], (const float*)d_in[18]};
  const float* b_[3]  = {(const float*)d_in[5],  (const float*)d_in[12], (const float*)d_in[19]};
  const float* gw[3]  = {(const float*)d_in[6],  (const float*)d_in[13], (const float*)d_in[20]};
  const float* gb[3]  = {(const float*)d_in[7],  (const float*)d_in[14], (const float*)d_in[21]};
  const float* ga[3]  = {(const float*)d_in[8],  (const float*)d_in[15], (const float*)d_in[22]};
  const float* mW0 = (const float*)d_in[23];
  const float* mb0 = (const float*)d_in[24];
  const float* mW1 = (const float*)d_in[25];
  const float* mb1 = (const float*)d_in[26];
  const float* mW2 = (const float*)d_in[27];
  const float* mb2 = (const float*)d_in[28];
  float* out = (float*)d_out;

  char* ws = (char*)d_ws;
  size_t off = 0;
  auto take = [&](size_t bytes) -> char* {
    char* p = ws + off;
    off = (off + bytes + 255) & ~(size_t)255;
    return p;
  };
  ushort* hb    = (ushort*)take((size_t)NN * FDIM * 2);
  ushort* aggb  = (ushort*)take((size_t)NN * FDIM * 2);
  float* bufD   = (float*)take((size_t)NN * CC * 4);
  ushort* Wt[3];
  for (int i = 0; i < 3; i++) Wt[i] = (ushort*)take((size_t)256 * 256 * 2);
  float* s_arr  = (float*)take((size_t)NN * HH * 4);
  float* d_arr  = (float*)take((size_t)NN * HH * 4);
  // zero-region: deg + 3 per-layer stat buffers (colsum|colsumsq each) -> ONE memset
  char* zbase   = (char*)take(0);
  int* deg      = (int*)take((size_t)NN * 4);
  float* cs[3];
  for (int i = 0; i < 3; i++) cs[i] = (float*)take(2048);   // [0:256)=colsum, [256:512)=colsumsq
  size_t zlen   = (size_t)(((char*)cs[2] + 2048) - zbase);
  int* cursor   = (int*)take((size_t)NN * 4);
  int* rowptr   = (int*)take((size_t)(NN + 1) * 4);
  int* csr_src  = (int*)take((size_t)ET * 4);
  int* bsum     = (int*)take(512);
  int* boff     = (int*)take(512);
  int* flag     = (int*)take(256);

  hipMemsetAsync(zbase, 0, zlen, stream);   // deg + all 3 layers' norm stats

  // CSR build (reused by all 3 layers)
  detect_kernel<<<1, 256, 0, stream>>>((const unsigned int*)ei, flag);
  degree_kernel<<<(ET + 255) / 256, 256, 0, stream>>>(ei, flag, deg);
  scan1_kernel<<<SCAN_NB, SCAN_BLK, 0, stream>>>(deg, rowptr, bsum);
  scan2_kernel<<<1, 128, 0, stream>>>(bsum, boff, rowptr);
  scan3_kernel<<<SCAN_NB, SCAN_BLK, 0, stream>>>(rowptr, cursor, boff);
  fill_kernel<<<(ET + 255) / 256, 256, 0, stream>>>(ei, flag, cursor, csr_src);

  // weight prep (x is consumed in f32 directly by layer-0 gemm)
  conv_w_kernel<<<dim3(4, 4, 3), 256, 0, stream>>>(W[0], W[1], W[2], Wt[0], Wt[1], Wt[2]);

  dim3 ggrid(256, 2);
  for (int L = 0; L < 3; L++) {
    if (L == 0)
      gemm_bf16<0><<<ggrid, 256, 0, stream>>>((const void*)x, Wt[0], hb,
                                              as_[0], ad_[0], s_arr, d_arr,
                                              nullptr, nullptr, nullptr, nullptr, nullptr);
    else
      gemm_bf16<1><<<ggrid, 256, 0, stream>>>((const void*)aggb, Wt[L], hb,
                                              as_[L], ad_[L], s_arr, d_arr,
                                              cs[L - 1], cs[L - 1] + 256,
                                              ga[L - 1], gw[L - 1], gb[L - 1]);
    if (L < 2) {
      agg_kernel<true><<<NN / 4, 256, 0, stream>>>(hb, s_arr, d_arr, rowptr, csr_src, b_[L], aggb);
      norm_reduce_bf<<<(NN + 127) / 128, 256, 0, stream>>>(aggb, cs[L], cs[L] + 256);
    } else {
      agg_kernel<false><<<NN / 4, 256, 0, stream>>>(hb, s_arr, d_arr, rowptr, csr_src, b_[L], bufD);
      norm_reduce_f32<<<(NN + 127) / 128, 256, 0, stream>>>(bufD, cs[2], cs[2] + 256);
    }
  }
  mlp_kernel<<<(NN + 255) / 256, 256, 0, stream>>>(bufD, cs[2], cs[2] + 256,
                                                   ga[2], gw[2], gb[2],
                                                   mW0, mb0, mW1, mb1, mW2, mb2, out);
}

// Round 14
// 741.066 us; speedup vs baseline: 1.0161x; 1.0161x over previous
//
#include <hip/hip_runtime.h>

#define NN 50000
#define EE 800000
#define ET 850000   // EE + NN self loops
#define HH 4
#define CC 64
#define FDIM 256    // HH*CC

#define SCAN_BLK 512
#define SCAN_NB ((NN + SCAN_BLK - 1) / SCAN_BLK)   // 98

typedef unsigned short ushort;
typedef __bf16 bf16x8 __attribute__((ext_vector_type(8)));
typedef float floatx4 __attribute__((ext_vector_type(4)));
typedef ushort ushort8v __attribute__((ext_vector_type(8)));
struct ushort4s { ushort x, y, z, w; };

__device__ __forceinline__ ushort f2bf(float f) {
  union { float f; unsigned u; } v; v.f = f;
  unsigned r = v.u + 0x7fffu + ((v.u >> 16) & 1u);  // RNE
  return (ushort)(r >> 16);
}
__device__ __forceinline__ float bf2f(ushort u) {
  return __uint_as_float(((unsigned)u) << 16);
}

// ---------- edge-index dtype handling (int32 vs int64 at runtime) ----------
__device__ __forceinline__ int get_edge(const void* p, int is64, long long idx) {
  if (is64) return (int)((const long long*)p)[idx];
  return ((const int*)p)[idx];
}

__global__ void detect_kernel(const unsigned int* p, int* flag) {
  // int64 with values < 50000 => every odd 32-bit word is 0
  __shared__ unsigned red[256];
  int t = threadIdx.x;
  unsigned o = 0;
  for (int i = 0; i < 4; i++) o |= p[(t * 4 + i) * 2 + 1];
  red[t] = o;
  __syncthreads();
  for (int s = 128; s > 0; s >>= 1) {
    if (t < s) red[t] |= red[t + s];
    __syncthreads();
  }
  if (t == 0) *flag = (red[0] == 0) ? 1 : 0;
}

// ---------- CSR build over dst ----------
__global__ void degree_kernel(const void* eidx, const int* flag, int* deg) {
  int k = blockIdx.x * blockDim.x + threadIdx.x;
  if (k >= ET) return;
  int is64 = *flag;
  int dst = (k < EE) ? get_edge(eidx, is64, (long long)EE + k) : (k - EE);
  atomicAdd(&deg[dst], 1);
}

__global__ __launch_bounds__(SCAN_BLK) void scan1_kernel(const int* __restrict__ deg,
                                                         int* __restrict__ rowptr,
                                                         int* __restrict__ bsum) {
  __shared__ int sm[SCAN_BLK];
  int t = threadIdx.x;
  int i = blockIdx.x * SCAN_BLK + t;
  int v = (i < NN) ? deg[i] : 0;
  sm[t] = v;
  __syncthreads();
#pragma unroll
  for (int o = 1; o < SCAN_BLK; o <<= 1) {
    int u = (t >= o) ? sm[t - o] : 0;
    __syncthreads();
    sm[t] += u;
    __syncthreads();
  }
  if (i < NN) rowptr[i] = sm[t] - v;                 // local exclusive
  if (t == SCAN_BLK - 1) bsum[blockIdx.x] = sm[t];   // block total
}

__global__ __launch_bounds__(128) void scan2_kernel(const int* __restrict__ bsum,
                                                    int* __restrict__ boff,
                                                    int* __restrict__ rowptr) {
  __shared__ int sm[128];
  int t = threadIdx.x;
  int v = (t < SCAN_NB) ? bsum[t] : 0;
  sm[t] = v;
  __syncthreads();
#pragma unroll
  for (int o = 1; o < 128; o <<= 1) {
    int u = (t >= o) ? sm[t - o] : 0;
    __syncthreads();
    sm[t] += u;
    __syncthreads();
  }
  if (t < SCAN_NB) boff[t] = sm[t] - v;  // exclusive block offset
  if (t == 0) rowptr[NN] = ET;
}

__global__ __launch_bounds__(SCAN_BLK) void scan3_kernel(int* __restrict__ rowptr,
                                                         int* __restrict__ cursor,
                                                         const int* __restrict__ boff) {
  int i = blockIdx.x * SCAN_BLK + threadIdx.x;
  if (i >= NN) return;
  int v = rowptr[i] + boff[blockIdx.x];
  rowptr[i] = v;
  cursor[i] = v;
}

__global__ void fill_kernel(const void* eidx, const int* flag, int* cursor, int* csr_src) {
  int k = blockIdx.x * blockDim.x + threadIdx.x;
  if (k >= ET) return;
  int is64 = *flag;
  int src, dst;
  if (k < EE) {
    src = get_edge(eidx, is64, k);
    dst = get_edge(eidx, is64, (long long)EE + k);
  } else {
    src = dst = k - EE;
  }
  int pos = atomicAdd(&cursor[dst], 1);
  csr_src[pos] = src;
}

// ---------- weight transpose via LDS tiles (coalesced reads AND writes) ----------
__global__ __launch_bounds__(256) void conv_w_kernel(const float* __restrict__ W0,
                                                     const float* __restrict__ W1,
                                                     const float* __restrict__ W2,
                                                     ushort* __restrict__ T0,
                                                     ushort* __restrict__ T1,
                                                     ushort* __restrict__ T2) {
  __shared__ float tile[64][65];
  const float* W = (blockIdx.z == 0) ? W0 : (blockIdx.z == 1) ? W1 : W2;
  ushort* Wt = (blockIdx.z == 0) ? T0 : (blockIdx.z == 1) ? T1 : T2;
  int bi = blockIdx.x * 64;   // k-base
  int bj = blockIdx.y * 64;   // n-base
  int tn = threadIdx.x & 63;
  int tr = threadIdx.x >> 6;
  for (int r = tr; r < 64; r += 4)
    tile[r][tn] = W[(size_t)(bi + r) * 256 + bj + tn];
  __syncthreads();
  for (int r = tr; r < 64; r += 4)
    Wt[(size_t)(bj + r) * 256 + bi + tn] = f2bf(tile[tn][r]);
}

// ---------- bf16 MFMA GEMM: B-panel staged in LDS ONCE, barrier-free row loop ----------
// C[M,256] = A[M,256] @ B[256,256] (B given transposed as Bt[n][k]).
// grid (256, 4): blockIdx.y = head, block covers cols head*64..+64.
// Block = 4 waves; B-panel 64 cols x 256 k = 32 KB LDS in MFMA-frag order,
// staged once (wave w stages col-subtile w, kb=0..7) + ONE barrier.
// Then grid-stride row loop (64 rows/block-iter, wave w rows +w*16): per iter
// 8 independent 16-B A-loads + 32 conflict-free ds_read_b128 + 32 MFMAs +
// stores. NO barriers in the loop -> next-iter A-loads pipeline under MFMAs
// (every prior variant either drained vmcnt at 16 barriers/block or chained
// 48 L2 loads per tile; R13 showed the allocator won't pin B in registers).
// MODE 0: A f32 (layer 0). MODE 1: A bf16 agg output, GraphNorm+LeakyReLU
// fused into the A-load (sc/sh in LDS, loop-invariant).
// Epilogue: (row,head) unique per wave-iter -> plain s/d stores.
template <int MODE>
__global__ __launch_bounds__(256) void gemm_bf16(const void* __restrict__ Ap,
                                                 const ushort* __restrict__ Bt,
                                                 ushort* __restrict__ C,
                                                 const float* __restrict__ as_,
                                                 const float* __restrict__ ad_,
                                                 float* __restrict__ s_arr,
                                                 float* __restrict__ d_arr,
                                                 const float* __restrict__ colsum,
                                                 const float* __restrict__ colsumsq,
                                                 const float* __restrict__ ga,
                                                 const float* __restrict__ gw,
                                                 const float* __restrict__ gb) {
  __shared__ ushort Bs[32 * 512];          // 32 KB: frag-group g = s*8+kb at g*512 + l*8
  __shared__ float scs[FDIM], shs[FDIM];
  int tid = threadIdx.x, w = tid >> 6, l = tid & 63;
  int lm = l & 15, lk = (l >> 4) * 8;
  int col0 = blockIdx.y * 64;
  int head = blockIdx.y;
  int quad = l >> 4;

  if constexpr (MODE == 1) {
    const float invn = 1.0f / (float)NN;
    float mu = colsum[tid] * invn;
    float ex2 = colsumsq[tid] * invn;
    float a = ga[tid];
    float var = fmaxf(ex2 - (2.f * a - a * a) * mu * mu, 0.f);
    float s = gw[tid] * rsqrtf(var + 1e-5f);
    scs[tid] = s;
    shs[tid] = gb[tid] - s * a * mu;
  }
  // stage B panel: wave w stages col-subtile s=w, all 8 k-blocks
  {
    const ushort* bp = Bt + (size_t)(col0 + w * 16 + lm) * 256 + lk;
#pragma unroll
    for (int kb = 0; kb < 8; kb++)
      *(ushort8v*)&Bs[(w * 8 + kb) * 512 + l * 8] = *(const ushort8v*)(bp + kb * 32);
  }
  __syncthreads();   // the only barrier in the kernel

  float asv[4], adv[4];
#pragma unroll
  for (int s = 0; s < 4; s++) {
    asv[s] = as_[col0 + s * 16 + lm];
    adv[s] = ad_[col0 + s * 16 + lm];
  }

  for (int rt = blockIdx.x * 64; rt < NN; rt += gridDim.x * 64) {
    int row0 = rt + w * 16;
    int arow = min(row0 + lm, NN - 1);
    bf16x8 afr[8];
    if constexpr (MODE == 0) {
      const float* ap = (const float*)Ap + (size_t)arow * 256 + lk;
#pragma unroll
      for (int kb = 0; kb < 8; kb++) {
        float4 u = *(const float4*)(ap + kb * 32);
        float4 v = *(const float4*)(ap + kb * 32 + 4);
        ushort8v t = ushort8v{f2bf(u.x), f2bf(u.y), f2bf(u.z), f2bf(u.w),
                              f2bf(v.x), f2bf(v.y), f2bf(v.z), f2bf(v.w)};
        afr[kb] = *(bf16x8*)&t;
      }
    } else {
      const ushort* ap = (const ushort*)Ap + (size_t)arow * 256 + lk;
#pragma unroll
      for (int kb = 0; kb < 8; kb++) {
        ushort8v r = *(const ushort8v*)(ap + kb * 32);
        ushort8v t;
        int kbase = kb * 32 + lk;
#pragma unroll
        for (int j = 0; j < 8; j++) {
          float y = fmaf(scs[kbase + j], bf2f(r[j]), shs[kbase + j]);
          y = fmaxf(y, 0.01f * y);   // LeakyReLU(0.01)
          t[j] = f2bf(y);
        }
        afr[kb] = *(bf16x8*)&t;
      }
    }
    floatx4 acc[4];
#pragma unroll
    for (int s = 0; s < 4; s++) acc[s] = floatx4{0.f, 0.f, 0.f, 0.f};
#pragma unroll
    for (int kb = 0; kb < 8; kb++) {
      bf16x8 bf[4];
#pragma unroll
      for (int s = 0; s < 4; s++) bf[s] = *(const bf16x8*)&Bs[(s * 8 + kb) * 512 + l * 8];
#pragma unroll
      for (int s = 0; s < 4; s++)
        acc[s] = __builtin_amdgcn_mfma_f32_16x16x32_bf16(afr[kb], bf[s], acc[s], 0, 0, 0);
    }

    // ----- C store -----
#pragma unroll
    for (int s = 0; s < 4; s++) {
      int col = col0 + s * 16 + lm;
#pragma unroll
      for (int r = 0; r < 4; r++) {
        int row = row0 + quad * 4 + r;
        if (row < NN) C[(size_t)row * 256 + col] = f2bf(acc[s][r]);
      }
    }
    // ----- s/d epilogue -----
#pragma unroll
    for (int r = 0; r < 4; r++) {
      float sp = acc[0][r] * asv[0] + acc[1][r] * asv[1] +
                 acc[2][r] * asv[2] + acc[3][r] * asv[3];
      float dp = acc[0][r] * adv[0] + acc[1][r] * adv[1] +
                 acc[2][r] * adv[2] + acc[3][r] * adv[3];
      sp += __shfl_xor(sp, 1); dp += __shfl_xor(dp, 1);
      sp += __shfl_xor(sp, 2); dp += __shfl_xor(dp, 2);
      sp += __shfl_xor(sp, 4); dp += __shfl_xor(dp, 4);
      sp += __shfl_xor(sp, 8); dp += __shfl_xor(dp, 8);
      if (lm == 0) {
        int row = row0 + quad * 4 + r;
        if (row < NN) {
          s_arr[row * HH + head] = sp;
          d_arr[row * HH + head] = dp;
        }
      }
    }
  }
}

// ---------- aggregation: one wave per node, all heads; fused edge softmax ----------
template <bool CONCAT>
__global__ __launch_bounds__(256) void agg_kernel(const ushort* __restrict__ hb,
                                                  const float* __restrict__ s_arr,
                                                  const float* __restrict__ d_arr,
                                                  const int* __restrict__ rowptr,
                                                  const int* __restrict__ csr_src,
                                                  const float* __restrict__ bias,
                                                  void* __restrict__ outp) {
  int w = __builtin_amdgcn_readfirstlane(threadIdx.x >> 6);
  int l = threadIdx.x & 63;
  int head = l >> 4;
  int n = blockIdx.x * 4 + w;
  int beg = rowptr[n], end = rowptr[n + 1];
  float dh = d_arr[n * HH + head];
  float a0 = 0.f, a1 = 0.f, a2 = 0.f, a3 = 0.f, den = 0.f;

  int i = beg;
  for (; i + 8 <= end; i += 8) {
    int s0 = csr_src[i], s1 = csr_src[i + 1], s2 = csr_src[i + 2], s3 = csr_src[i + 3];
    int s4 = csr_src[i + 4], s5 = csr_src[i + 5], s6 = csr_src[i + 6], s7 = csr_src[i + 7];
    float e0 = s_arr[s0 * HH + head] + dh;
    float e1 = s_arr[s1 * HH + head] + dh;
    float e2 = s_arr[s2 * HH + head] + dh;
    float e3 = s_arr[s3 * HH + head] + dh;
    float e4 = s_arr[s4 * HH + head] + dh;
    float e5 = s_arr[s5 * HH + head] + dh;
    float e6 = s_arr[s6 * HH + head] + dh;
    float e7 = s_arr[s7 * HH + head] + dh;
    ushort4s h0 = *(const ushort4s*)(hb + (unsigned)(s0 * FDIM + l * 4));
    ushort4s h1 = *(const ushort4s*)(hb + (unsigned)(s1 * FDIM + l * 4));
    ushort4s h2 = *(const ushort4s*)(hb + (unsigned)(s2 * FDIM + l * 4));
    ushort4s h3 = *(const ushort4s*)(hb + (unsigned)(s3 * FDIM + l * 4));
    ushort4s h4 = *(const ushort4s*)(hb + (unsigned)(s4 * FDIM + l * 4));
    ushort4s h5 = *(const ushort4s*)(hb + (unsigned)(s5 * FDIM + l * 4));
    ushort4s h6 = *(const ushort4s*)(hb + (unsigned)(s6 * FDIM + l * 4));
    ushort4s h7 = *(const ushort4s*)(hb + (unsigned)(s7 * FDIM + l * 4));
    e0 = (e0 > 0.f) ? e0 : 0.2f * e0;  float w0 = __expf(e0);
    e1 = (e1 > 0.f) ? e1 : 0.2f * e1;  float w1 = __expf(e1);
    e2 = (e2 > 0.f) ? e2 : 0.2f * e2;  float w2 = __expf(e2);
    e3 = (e3 > 0.f) ? e3 : 0.2f * e3;  float w3 = __expf(e3);
    e4 = (e4 > 0.f) ? e4 : 0.2f * e4;  float w4 = __expf(e4);
    e5 = (e5 > 0.f) ? e5 : 0.2f * e5;  float w5 = __expf(e5);
    e6 = (e6 > 0.f) ? e6 : 0.2f * e6;  float w6 = __expf(e6);
    e7 = (e7 > 0.f) ? e7 : 0.2f * e7;  float w7 = __expf(e7);
    den += ((w0 + w1) + (w2 + w3)) + ((w4 + w5) + (w6 + w7));
    a0 = fmaf(w0, bf2f(h0.x), a0); a1 = fmaf(w0, bf2f(h0.y), a1);
    a2 = fmaf(w0, bf2f(h0.z), a2); a3 = fmaf(w0, bf2f(h0.w), a3);
    a0 = fmaf(w1, bf2f(h1.x), a0); a1 = fmaf(w1, bf2f(h1.y), a1);
    a2 = fmaf(w1, bf2f(h1.z), a2); a3 = fmaf(w1, bf2f(h1.w), a3);
    a0 = fmaf(w2, bf2f(h2.x), a0); a1 = fmaf(w2, bf2f(h2.y), a1);
    a2 = fmaf(w2, bf2f(h2.z), a2); a3 = fmaf(w2, bf2f(h2.w), a3);
    a0 = fmaf(w3, bf2f(h3.x), a0); a1 = fmaf(w3, bf2f(h3.y), a1);
    a2 = fmaf(w3, bf2f(h3.z), a2); a3 = fmaf(w3, bf2f(h3.w), a3);
    a0 = fmaf(w4, bf2f(h4.x), a0); a1 = fmaf(w4, bf2f(h4.y), a1);
    a2 = fmaf(w4, bf2f(h4.z), a2); a3 = fmaf(w4, bf2f(h4.w), a3);
    a0 = fmaf(w5, bf2f(h5.x), a0); a1 = fmaf(w5, bf2f(h5.y), a1);
    a2 = fmaf(w5, bf2f(h5.z), a2); a3 = fmaf(w5, bf2f(h5.w), a3);
    a0 = fmaf(w6, bf2f(h6.x), a0); a1 = fmaf(w6, bf2f(h6.y), a1);
    a2 = fmaf(w6, bf2f(h6.z), a2); a3 = fmaf(w6, bf2f(h6.w), a3);
    a0 = fmaf(w7, bf2f(h7.x), a0); a1 = fmaf(w7, bf2f(h7.y), a1);
    a2 = fmaf(w7, bf2f(h7.z), a2); a3 = fmaf(w7, bf2f(h7.w), a3);
  }
  for (; i + 4 <= end; i += 4) {
    int s0 = csr_src[i], s1 = csr_src[i + 1], s2 = csr_src[i + 2], s3 = csr_src[i + 3];
    float e0 = s_arr[s0 * HH + head] + dh;
    float e1 = s_arr[s1 * HH + head] + dh;
    float e2 = s_arr[s2 * HH + head] + dh;
    float e3 = s_arr[s3 * HH + head] + dh;
    ushort4s h0 = *(const ushort4s*)(hb + (unsigned)(s0 * FDIM + l * 4));
    ushort4s h1 = *(const ushort4s*)(hb + (unsigned)(s1 * FDIM + l * 4));
    ushort4s h2 = *(const ushort4s*)(hb + (unsigned)(s2 * FDIM + l * 4));
    ushort4s h3 = *(const ushort4s*)(hb + (unsigned)(s3 * FDIM + l * 4));
    e0 = (e0 > 0.f) ? e0 : 0.2f * e0;  float w0 = __expf(e0);
    e1 = (e1 > 0.f) ? e1 : 0.2f * e1;  float w1 = __expf(e1);
    e2 = (e2 > 0.f) ? e2 : 0.2f * e2;  float w2 = __expf(e2);
    e3 = (e3 > 0.f) ? e3 : 0.2f * e3;  float w3 = __expf(e3);
    den += (w0 + w1) + (w2 + w3);
    a0 = fmaf(w0, bf2f(h0.x), a0); a1 = fmaf(w0, bf2f(h0.y), a1);
    a2 = fmaf(w0, bf2f(h0.z), a2); a3 = fmaf(w0, bf2f(h0.w), a3);
    a0 = fmaf(w1, bf2f(h1.x), a0); a1 = fmaf(w1, bf2f(h1.y), a1);
    a2 = fmaf(w1, bf2f(h1.z), a2); a3 = fmaf(w1, bf2f(h1.w), a3);
    a0 = fmaf(w2, bf2f(h2.x), a0); a1 = fmaf(w2, bf2f(h2.y), a1);
    a2 = fmaf(w2, bf2f(h2.z), a2); a3 = fmaf(w2, bf2f(h2.w), a3);
    a0 = fmaf(w3, bf2f(h3.x), a0); a1 = fmaf(w3, bf2f(h3.y), a1);
    a2 = fmaf(w3, bf2f(h3.z), a2); a3 = fmaf(w3, bf2f(h3.w), a3);
  }
  for (; i < end; i++) {
    int s0 = csr_src[i];
    float e0 = s_arr[s0 * HH + head] + dh;
    ushort4s h0 = *(const ushort4s*)(hb + (unsigned)(s0 * FDIM + l * 4));
    e0 = (e0 > 0.f) ? e0 : 0.2f * e0;
    float w0 = __expf(e0);
    den += w0;
    a0 = fmaf(w0, bf2f(h0.x), a0); a1 = fmaf(w0, bf2f(h0.y), a1);
    a2 = fmaf(w0, bf2f(h0.z), a2); a3 = fmaf(w0, bf2f(h0.w), a3);
  }
  float inv = 1.0f / den;  // self loop guarantees den > 0
  float r0 = a0 * inv, r1 = a1 * inv, r2 = a2 * inv, r3 = a3 * inv;

  if (CONCAT) {
    float4 bv = ((const float4*)bias)[l];
    ushort4s o;
    o.x = f2bf(r0 + bv.x); o.y = f2bf(r1 + bv.y);
    o.z = f2bf(r2 + bv.z); o.w = f2bf(r3 + bv.w);
    ((ushort4s*)outp)[(unsigned)(n * 64 + l)] = o;
  } else {
    r0 += __shfl_xor(r0, 16); r1 += __shfl_xor(r1, 16);
    r2 += __shfl_xor(r2, 16); r3 += __shfl_xor(r3, 16);
    r0 += __shfl_xor(r0, 32); r1 += __shfl_xor(r1, 32);
    r2 += __shfl_xor(r2, 32); r3 += __shfl_xor(r3, 32);
    if (l < 16) {
      float4 bv = ((const float4*)bias)[l];
      float4 o;
      o.x = 0.25f * r0 + bv.x; o.y = 0.25f * r1 + bv.y;
      o.z = 0.25f * r2 + bv.z; o.w = 0.25f * r3 + bv.w;
      ((float4*)outp)[(unsigned)(n * 16 + l)] = o;
    }
  }
}

// ---------- GraphNorm reduce ----------
__global__ __launch_bounds__(256) void norm_reduce_bf(const ushort* __restrict__ xin,
                                                      float* colsum, float* colsumsq) {
  __shared__ float4 sm1[256], sm2[256];
  int t = threadIdx.x;
  int c4 = (t & 63) * 4;
  int rl = t >> 6;
  int r0 = blockIdx.x * 128;
  int r1 = min(NN, r0 + 128);
  float s0 = 0.f, s1 = 0.f, s2 = 0.f, s3 = 0.f;
  float q0 = 0.f, q1 = 0.f, q2 = 0.f, q3 = 0.f;
  for (int r = r0 + rl; r < r1; r += 4) {
    ushort4s v = *(const ushort4s*)(xin + (size_t)r * FDIM + c4);
    float f0 = bf2f(v.x), f1 = bf2f(v.y), f2 = bf2f(v.z), f3 = bf2f(v.w);
    s0 += f0; q0 += f0 * f0;
    s1 += f1; q1 += f1 * f1;
    s2 += f2; q2 += f2 * f2;
    s3 += f3; q3 += f3 * f3;
  }
  sm1[t] = float4{s0, s1, s2, s3};
  sm2[t] = float4{q0, q1, q2, q3};
  __syncthreads();
  if (t < 64) {
    float4 a = sm1[t], b = sm1[t + 64], c = sm1[t + 128], d = sm1[t + 192];
    atomicAdd(&colsum[c4 + 0], a.x + b.x + c.x + d.x);
    atomicAdd(&colsum[c4 + 1], a.y + b.y + c.y + d.y);
    atomicAdd(&colsum[c4 + 2], a.z + b.z + c.z + d.z);
    atomicAdd(&colsum[c4 + 3], a.w + b.w + c.w + d.w);
    float4 e = sm2[t], f = sm2[t + 64], g = sm2[t + 128], h = sm2[t + 192];
    atomicAdd(&colsumsq[c4 + 0], e.x + f.x + g.x + h.x);
    atomicAdd(&colsumsq[c4 + 1], e.y + f.y + g.y + h.y);
    atomicAdd(&colsumsq[c4 + 2], e.z + f.z + g.z + h.z);
    atomicAdd(&colsumsq[c4 + 3], e.w + f.w + g.w + h.w);
  }
}

__global__ __launch_bounds__(256) void norm_reduce_f32(const float* __restrict__ xin,
                                                       float* colsum, float* colsumsq) {
  int f = threadIdx.x & (CC - 1);
  int rl = threadIdx.x / CC;
  int r0 = blockIdx.x * 128;
  int r1 = min(NN, r0 + 128);
  float s1 = 0.f, s2 = 0.f;
  for (int r = r0 + rl; r < r1; r += 4) {
    float v = xin[(size_t)r * CC + f];
    s1 += v; s2 += v * v;
  }
  atomicAdd(&colsum[f], s1);
  atomicAdd(&colsumsq[f], s2);
}

// ---------- MLP 64->32->16->2 with fused GraphNorm+LeakyReLU on input ----------
__global__ __launch_bounds__(256) void mlp_kernel(const float* __restrict__ xin,
                                                  const float* __restrict__ colsum,
                                                  const float* __restrict__ colsumsq,
                                                  const float* __restrict__ ga,
                                                  const float* __restrict__ gw,
                                                  const float* __restrict__ gb,
                                                  const float* mW0, const float* mb0,
                                                  const float* mW1, const float* mb1,
                                                  const float* mW2, const float* mb2,
                                                  float* __restrict__ out) {
  __shared__ float W0s[64 * 32];
  __shared__ float W1s[32 * 16];
  __shared__ float W2s[16 * 2];
  __shared__ float b0s[32], b1s[16], b2s[2];
  __shared__ float sc[CC], sh[CC];
  int t = threadIdx.x;
  for (int i = t; i < 2048; i += 256) W0s[i] = mW0[i];
  for (int i = t; i < 512; i += 256) W1s[i] = mW1[i];
  if (t < 32) { W2s[t] = mW2[t]; b0s[t] = mb0[t]; }
  if (t < 16) b1s[t] = mb1[t];
  if (t < 2) b2s[t] = mb2[t];
  if (t < CC) {
    const float invn = 1.0f / (float)NN;
    float mu = colsum[t] * invn;
    float ex2 = colsumsq[t] * invn;
    float a = ga[t];
    float var = fmaxf(ex2 - (2.f * a - a * a) * mu * mu, 0.f);
    float s = gw[t] * rsqrtf(var + 1e-5f);
    sc[t] = s; sh[t] = gb[t] - s * a * mu;
  }
  __syncthreads();
  int node = blockIdx.x * 256 + t;
  if (node >= NN) return;
  float in[64];
  const float* xr = xin + (size_t)node * 64;
#pragma unroll
  for (int k = 0; k < 64; k++) {
    float y = sc[k] * xr[k] + sh[k];
    in[k] = (y > 0.f) ? y : 0.01f * y;   // GraphNorm + LeakyReLU(0.01) fused
  }
  float h1[32];
#pragma unroll
  for (int j = 0; j < 32; j++) h1[j] = b0s[j];
#pragma unroll
  for (int k = 0; k < 64; k++) {
    float v = in[k];
#pragma unroll
    for (int j = 0; j < 32; j++) h1[j] += v * W0s[k * 32 + j];
  }
#pragma unroll
  for (int j = 0; j < 32; j++) h1[j] = fmaxf(h1[j], 0.f);
  float h2[16];
#pragma unroll
  for (int j = 0; j < 16; j++) h2[j] = b1s[j];
#pragma unroll
  for (int k = 0; k < 32; k++) {
    float v = h1[k];
#pragma unroll
    for (int j = 0; j < 16; j++) h2[j] += v * W1s[k * 16 + j];
  }
#pragma unroll
  for (int j = 0; j < 16; j++) h2[j] = fmaxf(h2[j], 0.f);
  float o0 = b2s[0], o1 = b2s[1];
#pragma unroll
  for (int k = 0; k < 16; k++) {
    o0 += h2[k] * W2s[k * 2 + 0];
    o1 += h2[k] * W2s[k * 2 + 1];
  }
  out[(size_t)node * 2 + 0] = o0;
  out[(size_t)node * 2 + 1] = o1;
}

extern "C" void kernel_launch(void* const* d_in, const int* in_sizes, int n_in,
                              void* d_out, int out_size, void* d_ws, size_t ws_size,
                              hipStream_t stream) {
  const float* x = (const float*)d_in[0];
  const void* ei = d_in[1];
  const float* W[3]   = {(const float*)d_in[2],  (const float*)d_in[9],  (const float*)d_in[16]};
  const float* as_[3] = {(const float*)d_in[3],  (const float*)d_in[10], (const float*)d_in[17]};
  const float* ad_[3] = {(const float*)d_in[4],  (const float*)d_in[11], (const float*)d_in[18]};
  const float* b_[3]  = {(const float*)d_in[5],  (const float*)d_in[12], (const float*)d_in[19]};
  const float* gw[3]  = {(const float*)d_in[6],  (const float*)d_in[13], (const float*)d_in[20]};
  const float* gb[3]  = {(const float*)d_in[7],  (const float*)d_in[14], (const float*)d_in[21]};
  const float* ga[3]  = {(const float*)d_in[8],  (const float*)d_in[15], (const float*)d_in[22]};
  const float* mW0 = (const float*)d_in[23];
  const float* mb0 = (const float*)d_in[24];
  const float* mW1 = (const float*)d_in[25];
  const float* mb1 = (const float*)d_in[26];
  const float* mW2 = (const float*)d_in[27];
  const float* mb2 = (const float*)d_in[28];
  float* out = (float*)d_out;

  char* ws = (char*)d_ws;
  size_t off = 0;
  auto take = [&](size_t bytes) -> char* {
    char* p = ws + off;
    off = (off + bytes + 255) & ~(size_t)255;
    return p;
  };
  ushort* hb    = (ushort*)take((size_t)NN * FDIM * 2);
  ushort* aggb  = (ushort*)take((size_t)NN * FDIM * 2);
  float* bufD   = (float*)take((size_t)NN * CC * 4);
  ushort* Wt[3];
  for (int i = 0; i < 3; i++) Wt[i] = (ushort*)take((size_t)256 * 256 * 2);
  float* s_arr  = (float*)take((size_t)NN * HH * 4);
  float* d_arr  = (float*)take((size_t)NN * HH * 4);
  // zero-region: deg + 3 per-layer stat buffers (colsum|colsumsq each) -> ONE memset
  char* zbase   = (char*)take(0);
  int* deg      = (int*)take((size_t)NN * 4);
  float* cs[3];
  for (int i = 0; i < 3; i++) cs[i] = (float*)take(2048);   // [0:256)=colsum, [256:512)=colsumsq
  size_t zlen   = (size_t)(((char*)cs[2] + 2048) - zbase);
  int* cursor   = (int*)take((size_t)NN * 4);
  int* rowptr   = (int*)take((size_t)(NN + 1) * 4);
  int* csr_src  = (int*)take((size_t)ET * 4);
  int* bsum     = (int*)take(512);
  int* boff     = (int*)take(512);
  int* flag     = (int*)take(256);

  hipMemsetAsync(zbase, 0, zlen, stream);   // deg + all 3 layers' norm stats

  // CSR build (reused by all 3 layers)
  detect_kernel<<<1, 256, 0, stream>>>((const unsigned int*)ei, flag);
  degree_kernel<<<(ET + 255) / 256, 256, 0, stream>>>(ei, flag, deg);
  scan1_kernel<<<SCAN_NB, SCAN_BLK, 0, stream>>>(deg, rowptr, bsum);
  scan2_kernel<<<1, 128, 0, stream>>>(bsum, boff, rowptr);
  scan3_kernel<<<SCAN_NB, SCAN_BLK, 0, stream>>>(rowptr, cursor, boff);
  fill_kernel<<<(ET + 255) / 256, 256, 0, stream>>>(ei, flag, cursor, csr_src);

  // weight prep (x is consumed in f32 directly by layer-0 gemm)
  conv_w_kernel<<<dim3(4, 4, 3), 256, 0, stream>>>(W[0], W[1], W[2], Wt[0], Wt[1], Wt[2]);

  dim3 ggrid(256, 4);
  for (int L = 0; L < 3; L++) {
    if (L == 0)
      gemm_bf16<0><<<ggrid, 256, 0, stream>>>((const void*)x, Wt[0], hb,
                                              as_[0], ad_[0], s_arr, d_arr,
                                              nullptr, nullptr, nullptr, nullptr, nullptr);
    else
      gemm_bf16<1><<<ggrid, 256, 0, stream>>>((const void*)aggb, Wt[L], hb,
                                              as_[L], ad_[L], s_arr, d_arr,
                                              cs[L - 1], cs[L - 1] + 256,
                                              ga[L - 1], gw[L - 1], gb[L - 1]);
    if (L < 2) {
      agg_kernel<true><<<NN / 4, 256, 0, stream>>>(hb, s_arr, d_arr, rowptr, csr_src, b_[L], aggb);
      norm_reduce_bf<<<(NN + 127) / 128, 256, 0, stream>>>(aggb, cs[L], cs[L] + 256);
    } else {
      agg_kernel<false><<<NN / 4, 256, 0, stream>>>(hb, s_arr, d_arr, rowptr, csr_src, b_[L], bufD);
      norm_reduce_f32<<<(NN + 127) / 128, 256, 0, stream>>>(bufD, cs[2], cs[2] + 256);
    }
  }
  mlp_kernel<<<(NN + 255) / 256, 256, 0, stream>>>(bufD, cs[2], cs[2] + 256,
                                                   ga[2], gw[2], gb[2],
                                                   mW0, mb0, mW1, mb1, mW2, mb2, out);
}

// Round 15
// 683.917 us; speedup vs baseline: 1.1010x; 1.0836x over previous
//
#include <hip/hip_runtime.h>

#define NN 50000
#define EE 800000
#define ET 850000   // EE + NN self loops
#define HH 4
#define CC 64
#define FDIM 256    // HH*CC

#define SCAN_BLK 512
#define SCAN_NB ((NN + SCAN_BLK - 1) / SCAN_BLK)   // 98

typedef unsigned short ushort;
typedef __bf16 bf16x8 __attribute__((ext_vector_type(8)));
typedef float floatx4 __attribute__((ext_vector_type(4)));
typedef ushort ushort8v __attribute__((ext_vector_type(8)));
struct ushort4s { ushort x, y, z, w; };

__device__ __forceinline__ ushort f2bf(float f) {
  union { float f; unsigned u; } v; v.f = f;
  unsigned r = v.u + 0x7fffu + ((v.u >> 16) & 1u);  // RNE
  return (ushort)(r >> 16);
}
__device__ __forceinline__ float bf2f(ushort u) {
  return __uint_as_float(((unsigned)u) << 16);
}

// ---------- edge-index dtype handling (int32 vs int64 at runtime) ----------
__device__ __forceinline__ int get_edge(const void* p, int is64, long long idx) {
  if (is64) return (int)((const long long*)p)[idx];
  return ((const int*)p)[idx];
}

__global__ void detect_kernel(const unsigned int* p, int* flag) {
  // int64 with values < 50000 => every odd 32-bit word is 0
  __shared__ unsigned red[256];
  int t = threadIdx.x;
  unsigned o = 0;
  for (int i = 0; i < 4; i++) o |= p[(t * 4 + i) * 2 + 1];
  red[t] = o;
  __syncthreads();
  for (int s = 128; s > 0; s >>= 1) {
    if (t < s) red[t] |= red[t + s];
    __syncthreads();
  }
  if (t == 0) *flag = (red[0] == 0) ? 1 : 0;
}

// ---------- CSR build over dst ----------
__global__ void degree_kernel(const void* eidx, const int* flag, int* deg) {
  int k = blockIdx.x * blockDim.x + threadIdx.x;
  if (k >= ET) return;
  int is64 = *flag;
  int dst = (k < EE) ? get_edge(eidx, is64, (long long)EE + k) : (k - EE);
  atomicAdd(&deg[dst], 1);
}

__global__ __launch_bounds__(SCAN_BLK) void scan1_kernel(const int* __restrict__ deg,
                                                         int* __restrict__ rowptr,
                                                         int* __restrict__ bsum) {
  __shared__ int sm[SCAN_BLK];
  int t = threadIdx.x;
  int i = blockIdx.x * SCAN_BLK + t;
  int v = (i < NN) ? deg[i] : 0;
  sm[t] = v;
  __syncthreads();
#pragma unroll
  for (int o = 1; o < SCAN_BLK; o <<= 1) {
    int u = (t >= o) ? sm[t - o] : 0;
    __syncthreads();
    sm[t] += u;
    __syncthreads();
  }
  if (i < NN) rowptr[i] = sm[t] - v;                 // local exclusive
  if (t == SCAN_BLK - 1) bsum[blockIdx.x] = sm[t];   // block total
}

__global__ __launch_bounds__(128) void scan2_kernel(const int* __restrict__ bsum,
                                                    int* __restrict__ boff,
                                                    int* __restrict__ rowptr) {
  __shared__ int sm[128];
  int t = threadIdx.x;
  int v = (t < SCAN_NB) ? bsum[t] : 0;
  sm[t] = v;
  __syncthreads();
#pragma unroll
  for (int o = 1; o < 128; o <<= 1) {
    int u = (t >= o) ? sm[t - o] : 0;
    __syncthreads();
    sm[t] += u;
    __syncthreads();
  }
  if (t < SCAN_NB) boff[t] = sm[t] - v;  // exclusive block offset
  if (t == 0) rowptr[NN] = ET;
}

__global__ __launch_bounds__(SCAN_BLK) void scan3_kernel(int* __restrict__ rowptr,
                                                         int* __restrict__ cursor,
                                                         const int* __restrict__ boff) {
  int i = blockIdx.x * SCAN_BLK + threadIdx.x;
  if (i >= NN) return;
  int v = rowptr[i] + boff[blockIdx.x];
  rowptr[i] = v;
  cursor[i] = v;
}

__global__ void fill_kernel(const void* eidx, const int* flag, int* cursor, int* csr_src) {
  int k = blockIdx.x * blockDim.x + threadIdx.x;
  if (k >= ET) return;
  int is64 = *flag;
  int src, dst;
  if (k < EE) {
    src = get_edge(eidx, is64, k);
    dst = get_edge(eidx, is64, (long long)EE + k);
  } else {
    src = dst = k - EE;
  }
  int pos = atomicAdd(&cursor[dst], 1);
  csr_src[pos] = src;
}

// all three weight transposes in one dispatch (grid.y selects the matrix)
__global__ void conv_w_kernel(const float* __restrict__ W0, const float* __restrict__ W1,
                              const float* __restrict__ W2,
                              ushort* __restrict__ T0, ushort* __restrict__ T1,
                              ushort* __restrict__ T2) {
  const float* W = (blockIdx.y == 0) ? W0 : (blockIdx.y == 1) ? W1 : W2;
  ushort* Wt = (blockIdx.y == 0) ? T0 : (blockIdx.y == 1) ? T1 : T2;
  int idx = blockIdx.x * 256 + threadIdx.x;  // 65536
  int k = idx >> 8, n = idx & 255;
  Wt[n * 256 + k] = f2bf(W[idx]);  // transpose: Wt[n][k]
}

// ---------- bf16 MFMA GEMM: small-tile + LDS (6 blocks/CU) + s/d epilogue ----------
// Block = 64 rows x 128 cols, 4 waves, wave tile 32x64 (2x4 16x16 subtiles).
// 1564 blocks = 6.1 blocks/CU: co-resident blocks' MFMA hides each other's
// barrier drains. Best measured gemm config (R12, total 683 us).
// MODE 0: A f32 (layer 0), inline cvt. MODE 1: A bf16 agg output, GraphNorm+
// LeakyReLU fused into staging from prev layer's colsum/colsumsq stats.
// Epilogue: wave w covers cols bcol0+(w&1)*64..+64 = one complete head ->
// plain stores of s,d (each (row,head) written by exactly one wave).
template <int MODE>
__global__ __launch_bounds__(256) void gemm_bf16(const void* __restrict__ Ap,
                                                 const ushort* __restrict__ Bt,
                                                 ushort* __restrict__ C,
                                                 const float* __restrict__ as_,
                                                 const float* __restrict__ ad_,
                                                 float* __restrict__ s_arr,
                                                 float* __restrict__ d_arr,
                                                 const float* __restrict__ colsum,
                                                 const float* __restrict__ colsumsq,
                                                 const float* __restrict__ ga,
                                                 const float* __restrict__ gw,
                                                 const float* __restrict__ gb) {
  __shared__ ushort As[4 * 512];
  __shared__ ushort Bs[8 * 512];
  __shared__ float scs[FDIM], shs[FDIM];
  int tid = threadIdx.x, w = tid >> 6, l = tid & 63;
  int brow0 = blockIdx.x * 64, bcol0 = blockIdx.y * 128;
  int lm = l & 15, lk = (l >> 4) * 8;
  // staging addresses: wave w -> A sub-tile w, B sub-tiles 2w, 2w+1
  int arA = min(brow0 + w * 16 + lm, NN - 1);
  size_t arowA = (size_t)arA * 256 + lk;
  const ushort* bg0 = Bt + (size_t)(bcol0 + (2 * w) * 16 + lm) * 256 + lk;
  const ushort* bg1 = Bt + (size_t)(bcol0 + (2 * w + 1) * 16 + lm) * 256 + lk;

  if constexpr (MODE == 1) {
    const float invn = 1.0f / (float)NN;
    float mu = colsum[tid] * invn;
    float ex2 = colsumsq[tid] * invn;
    float a = ga[tid];
    float var = fmaxf(ex2 - (2.f * a - a * a) * mu * mu, 0.f);
    float s = gw[tid] * rsqrtf(var + 1e-5f);
    scs[tid] = s;
    shs[tid] = gb[tid] - s * a * mu;
    __syncthreads();
  }

  floatx4 acc[2][4];
#pragma unroll
  for (int i = 0; i < 2; i++)
#pragma unroll
    for (int j = 0; j < 4; j++) acc[i][j] = floatx4{0.f, 0.f, 0.f, 0.f};

  int wm = (w >> 1) * 2, wn = (w & 1) * 4;   // wave: row sub-tiles wm..wm+1, col sub-tiles wn..wn+3

  for (int k0 = 0; k0 < 256; k0 += 32) {
    ushort8v a0;
    if constexpr (MODE == 0) {
      const float* p0 = (const float*)Ap + arowA + k0;
      float4 u0 = *(const float4*)p0, v0 = *(const float4*)(p0 + 4);
      a0 = ushort8v{f2bf(u0.x), f2bf(u0.y), f2bf(u0.z), f2bf(u0.w),
                    f2bf(v0.x), f2bf(v0.y), f2bf(v0.z), f2bf(v0.w)};
    } else {
      ushort8v r0 = *(const ushort8v*)((const ushort*)Ap + arowA + k0);
      int kb = k0 + lk;
#pragma unroll
      for (int j = 0; j < 8; j++) {
        float sc = scs[kb + j], sh = shs[kb + j];
        float y0 = fmaf(sc, bf2f(r0[j]), sh);
        y0 = fmaxf(y0, 0.01f * y0);   // LeakyReLU(0.01)
        a0[j] = f2bf(y0);
      }
    }
    ushort8v b0 = *(const ushort8v*)(bg0 + k0);
    ushort8v b1 = *(const ushort8v*)(bg1 + k0);
    *(ushort8v*)&As[w * 512 + l * 8] = a0;
    *(ushort8v*)&Bs[(2 * w) * 512 + l * 8] = b0;
    *(ushort8v*)&Bs[(2 * w + 1) * 512 + l * 8] = b1;
    __syncthreads();
    bf16x8 af[2], bfr[4];
#pragma unroll
    for (int i = 0; i < 2; i++) af[i] = *(const bf16x8*)&As[(wm + i) * 512 + l * 8];
#pragma unroll
    for (int j = 0; j < 4; j++) bfr[j] = *(const bf16x8*)&Bs[(wn + j) * 512 + l * 8];
#pragma unroll
    for (int i = 0; i < 2; i++)
#pragma unroll
      for (int j = 0; j < 4; j++)
        acc[i][j] = __builtin_amdgcn_mfma_f32_16x16x32_bf16(af[i], bfr[j], acc[i][j], 0, 0, 0);
    __syncthreads();
  }

  int quad = l >> 4;
  // ----- C store -----
#pragma unroll
  for (int i = 0; i < 2; i++) {
    int r0 = brow0 + (wm + i) * 16 + quad * 4;
#pragma unroll
    for (int j = 0; j < 4; j++) {
      int col = bcol0 + (wn + j) * 16 + lm;
#pragma unroll
      for (int r = 0; r < 4; r++) {
        int row = r0 + r;
        if (row < NN) C[(size_t)row * 256 + col] = f2bf(acc[i][j][r]);
      }
    }
  }
  // ----- s/d epilogue: this wave owns head (bcol0>>6)+(w&1) for its rows -----
  float asv[4], adv[4];
#pragma unroll
  for (int j = 0; j < 4; j++) {
    int col = bcol0 + (wn + j) * 16 + lm;
    asv[j] = as_[col];
    adv[j] = ad_[col];
  }
  int head = (bcol0 >> 6) + (w & 1);
#pragma unroll
  for (int i = 0; i < 2; i++) {
#pragma unroll
    for (int r = 0; r < 4; r++) {
      float sp = acc[i][0][r] * asv[0] + acc[i][1][r] * asv[1] +
                 acc[i][2][r] * asv[2] + acc[i][3][r] * asv[3];
      float dp = acc[i][0][r] * adv[0] + acc[i][1][r] * adv[1] +
                 acc[i][2][r] * adv[2] + acc[i][3][r] * adv[3];
      sp += __shfl_xor(sp, 1); dp += __shfl_xor(dp, 1);
      sp += __shfl_xor(sp, 2); dp += __shfl_xor(dp, 2);
      sp += __shfl_xor(sp, 4); dp += __shfl_xor(dp, 4);
      sp += __shfl_xor(sp, 8); dp += __shfl_xor(dp, 8);
      if (lm == 0) {
        int row = brow0 + (wm + i) * 16 + quad * 4 + r;
        if (row < NN) {
          s_arr[row * HH + head] = sp;   // plain store: unique (row,head) per wave
          d_arr[row * HH + head] = dp;
        }
      }
    }
  }
}

// ---------- aggregation: one wave per node, all heads; fused edge softmax ----------
// unroll 8: more gathers in flight per wave
template <bool CONCAT>
__global__ __launch_bounds__(256) void agg_kernel(const ushort* __restrict__ hb,
                                                  const float* __restrict__ s_arr,
                                                  const float* __restrict__ d_arr,
                                                  const int* __restrict__ rowptr,
                                                  const int* __restrict__ csr_src,
                                                  const float* __restrict__ bias,
                                                  void* __restrict__ outp) {
  int w = __builtin_amdgcn_readfirstlane(threadIdx.x >> 6);
  int l = threadIdx.x & 63;
  int head = l >> 4;
  int n = blockIdx.x * 4 + w;
  int beg = rowptr[n], end = rowptr[n + 1];
  float dh = d_arr[n * HH + head];
  float a0 = 0.f, a1 = 0.f, a2 = 0.f, a3 = 0.f, den = 0.f;

  int i = beg;
  for (; i + 8 <= end; i += 8) {
    int s0 = csr_src[i], s1 = csr_src[i + 1], s2 = csr_src[i + 2], s3 = csr_src[i + 3];
    int s4 = csr_src[i + 4], s5 = csr_src[i + 5], s6 = csr_src[i + 6], s7 = csr_src[i + 7];
    float e0 = s_arr[s0 * HH + head] + dh;
    float e1 = s_arr[s1 * HH + head] + dh;
    float e2 = s_arr[s2 * HH + head] + dh;
    float e3 = s_arr[s3 * HH + head] + dh;
    float e4 = s_arr[s4 * HH + head] + dh;
    float e5 = s_arr[s5 * HH + head] + dh;
    float e6 = s_arr[s6 * HH + head] + dh;
    float e7 = s_arr[s7 * HH + head] + dh;
    ushort4s h0 = *(const ushort4s*)(hb + (unsigned)(s0 * FDIM + l * 4));
    ushort4s h1 = *(const ushort4s*)(hb + (unsigned)(s1 * FDIM + l * 4));
    ushort4s h2 = *(const ushort4s*)(hb + (unsigned)(s2 * FDIM + l * 4));
    ushort4s h3 = *(const ushort4s*)(hb + (unsigned)(s3 * FDIM + l * 4));
    ushort4s h4 = *(const ushort4s*)(hb + (unsigned)(s4 * FDIM + l * 4));
    ushort4s h5 = *(const ushort4s*)(hb + (unsigned)(s5 * FDIM + l * 4));
    ushort4s h6 = *(const ushort4s*)(hb + (unsigned)(s6 * FDIM + l * 4));
    ushort4s h7 = *(const ushort4s*)(hb + (unsigned)(s7 * FDIM + l * 4));
    e0 = (e0 > 0.f) ? e0 : 0.2f * e0;  float w0 = __expf(e0);
    e1 = (e1 > 0.f) ? e1 : 0.2f * e1;  float w1 = __expf(e1);
    e2 = (e2 > 0.f) ? e2 : 0.2f * e2;  float w2 = __expf(e2);
    e3 = (e3 > 0.f) ? e3 : 0.2f * e3;  float w3 = __expf(e3);
    e4 = (e4 > 0.f) ? e4 : 0.2f * e4;  float w4 = __expf(e4);
    e5 = (e5 > 0.f) ? e5 : 0.2f * e5;  float w5 = __expf(e5);
    e6 = (e6 > 0.f) ? e6 : 0.2f * e6;  float w6 = __expf(e6);
    e7 = (e7 > 0.f) ? e7 : 0.2f * e7;  float w7 = __expf(e7);
    den += ((w0 + w1) + (w2 + w3)) + ((w4 + w5) + (w6 + w7));
    a0 = fmaf(w0, bf2f(h0.x), a0); a1 = fmaf(w0, bf2f(h0.y), a1);
    a2 = fmaf(w0, bf2f(h0.z), a2); a3 = fmaf(w0, bf2f(h0.w), a3);
    a0 = fmaf(w1, bf2f(h1.x), a0); a1 = fmaf(w1, bf2f(h1.y), a1);
    a2 = fmaf(w1, bf2f(h1.z), a2); a3 = fmaf(w1, bf2f(h1.w), a3);
    a0 = fmaf(w2, bf2f(h2.x), a0); a1 = fmaf(w2, bf2f(h2.y), a1);
    a2 = fmaf(w2, bf2f(h2.z), a2); a3 = fmaf(w2, bf2f(h2.w), a3);
    a0 = fmaf(w3, bf2f(h3.x), a0); a1 = fmaf(w3, bf2f(h3.y), a1);
    a2 = fmaf(w3, bf2f(h3.z), a2); a3 = fmaf(w3, bf2f(h3.w), a3);
    a0 = fmaf(w4, bf2f(h4.x), a0); a1 = fmaf(w4, bf2f(h4.y), a1);
    a2 = fmaf(w4, bf2f(h4.z), a2); a3 = fmaf(w4, bf2f(h4.w), a3);
    a0 = fmaf(w5, bf2f(h5.x), a0); a1 = fmaf(w5, bf2f(h5.y), a1);
    a2 = fmaf(w5, bf2f(h5.z), a2); a3 = fmaf(w5, bf2f(h5.w), a3);
    a0 = fmaf(w6, bf2f(h6.x), a0); a1 = fmaf(w6, bf2f(h6.y), a1);
    a2 = fmaf(w6, bf2f(h6.z), a2); a3 = fmaf(w6, bf2f(h6.w), a3);
    a0 = fmaf(w7, bf2f(h7.x), a0); a1 = fmaf(w7, bf2f(h7.y), a1);
    a2 = fmaf(w7, bf2f(h7.z), a2); a3 = fmaf(w7, bf2f(h7.w), a3);
  }
  for (; i + 4 <= end; i += 4) {
    int s0 = csr_src[i], s1 = csr_src[i + 1], s2 = csr_src[i + 2], s3 = csr_src[i + 3];
    float e0 = s_arr[s0 * HH + head] + dh;
    float e1 = s_arr[s1 * HH + head] + dh;
    float e2 = s_arr[s2 * HH + head] + dh;
    float e3 = s_arr[s3 * HH + head] + dh;
    ushort4s h0 = *(const ushort4s*)(hb + (unsigned)(s0 * FDIM + l * 4));
    ushort4s h1 = *(const ushort4s*)(hb + (unsigned)(s1 * FDIM + l * 4));
    ushort4s h2 = *(const ushort4s*)(hb + (unsigned)(s2 * FDIM + l * 4));
    ushort4s h3 = *(const ushort4s*)(hb + (unsigned)(s3 * FDIM + l * 4));
    e0 = (e0 > 0.f) ? e0 : 0.2f * e0;  float w0 = __expf(e0);
    e1 = (e1 > 0.f) ? e1 : 0.2f * e1;  float w1 = __expf(e1);
    e2 = (e2 > 0.f) ? e2 : 0.2f * e2;  float w2 = __expf(e2);
    e3 = (e3 > 0.f) ? e3 : 0.2f * e3;  float w3 = __expf(e3);
    den += (w0 + w1) + (w2 + w3);
    a0 = fmaf(w0, bf2f(h0.x), a0); a1 = fmaf(w0, bf2f(h0.y), a1);
    a2 = fmaf(w0, bf2f(h0.z), a2); a3 = fmaf(w0, bf2f(h0.w), a3);
    a0 = fmaf(w1, bf2f(h1.x), a0); a1 = fmaf(w1, bf2f(h1.y), a1);
    a2 = fmaf(w1, bf2f(h1.z), a2); a3 = fmaf(w1, bf2f(h1.w), a3);
    a0 = fmaf(w2, bf2f(h2.x), a0); a1 = fmaf(w2, bf2f(h2.y), a1);
    a2 = fmaf(w2, bf2f(h2.z), a2); a3 = fmaf(w2, bf2f(h2.w), a3);
    a0 = fmaf(w3, bf2f(h3.x), a0); a1 = fmaf(w3, bf2f(h3.y), a1);
    a2 = fmaf(w3, bf2f(h3.z), a2); a3 = fmaf(w3, bf2f(h3.w), a3);
  }
  for (; i < end; i++) {
    int s0 = csr_src[i];
    float e0 = s_arr[s0 * HH + head] + dh;
    ushort4s h0 = *(const ushort4s*)(hb + (unsigned)(s0 * FDIM + l * 4));
    e0 = (e0 > 0.f) ? e0 : 0.2f * e0;
    float w0 = __expf(e0);
    den += w0;
    a0 = fmaf(w0, bf2f(h0.x), a0); a1 = fmaf(w0, bf2f(h0.y), a1);
    a2 = fmaf(w0, bf2f(h0.z), a2); a3 = fmaf(w0, bf2f(h0.w), a3);
  }
  float inv = 1.0f / den;  // self loop guarantees den > 0
  float r0 = a0 * inv, r1 = a1 * inv, r2 = a2 * inv, r3 = a3 * inv;

  if (CONCAT) {
    float4 bv = ((const float4*)bias)[l];
    ushort4s o;
    o.x = f2bf(r0 + bv.x); o.y = f2bf(r1 + bv.y);
    o.z = f2bf(r2 + bv.z); o.w = f2bf(r3 + bv.w);
    ((ushort4s*)outp)[(unsigned)(n * 64 + l)] = o;
  } else {
    r0 += __shfl_xor(r0, 16); r1 += __shfl_xor(r1, 16);
    r2 += __shfl_xor(r2, 16); r3 += __shfl_xor(r3, 16);
    r0 += __shfl_xor(r0, 32); r1 += __shfl_xor(r1, 32);
    r2 += __shfl_xor(r2, 32); r3 += __shfl_xor(r3, 32);
    if (l < 16) {
      float4 bv = ((const float4*)bias)[l];
      float4 o;
      o.x = 0.25f * r0 + bv.x; o.y = 0.25f * r1 + bv.y;
      o.z = 0.25f * r2 + bv.z; o.w = 0.25f * r3 + bv.w;
      ((float4*)outp)[(unsigned)(n * 16 + l)] = o;
    }
  }
}

// ---------- GraphNorm reduce ----------
__global__ __launch_bounds__(256) void norm_reduce_bf(const ushort* __restrict__ xin,
                                                      float* colsum, float* colsumsq) {
  __shared__ float4 sm1[256], sm2[256];
  int t = threadIdx.x;
  int c4 = (t & 63) * 4;
  int rl = t >> 6;
  int r0 = blockIdx.x * 128;
  int r1 = min(NN, r0 + 128);
  float s0 = 0.f, s1 = 0.f, s2 = 0.f, s3 = 0.f;
  float q0 = 0.f, q1 = 0.f, q2 = 0.f, q3 = 0.f;
  for (int r = r0 + rl; r < r1; r += 4) {
    ushort4s v = *(const ushort4s*)(xin + (size_t)r * FDIM + c4);
    float f0 = bf2f(v.x), f1 = bf2f(v.y), f2 = bf2f(v.z), f3 = bf2f(v.w);
    s0 += f0; q0 += f0 * f0;
    s1 += f1; q1 += f1 * f1;
    s2 += f2; q2 += f2 * f2;
    s3 += f3; q3 += f3 * f3;
  }
  sm1[t] = float4{s0, s1, s2, s3};
  sm2[t] = float4{q0, q1, q2, q3};
  __syncthreads();
  if (t < 64) {
    float4 a = sm1[t], b = sm1[t + 64], c = sm1[t + 128], d = sm1[t + 192];
    atomicAdd(&colsum[c4 + 0], a.x + b.x + c.x + d.x);
    atomicAdd(&colsum[c4 + 1], a.y + b.y + c.y + d.y);
    atomicAdd(&colsum[c4 + 2], a.z + b.z + c.z + d.z);
    atomicAdd(&colsum[c4 + 3], a.w + b.w + c.w + d.w);
    float4 e = sm2[t], f = sm2[t + 64], g = sm2[t + 128], h = sm2[t + 192];
    atomicAdd(&colsumsq[c4 + 0], e.x + f.x + g.x + h.x);
    atomicAdd(&colsumsq[c4 + 1], e.y + f.y + g.y + h.y);
    atomicAdd(&colsumsq[c4 + 2], e.z + f.z + g.z + h.z);
    atomicAdd(&colsumsq[c4 + 3], e.w + f.w + g.w + h.w);
  }
}

__global__ __launch_bounds__(256) void norm_reduce_f32(const float* __restrict__ xin,
                                                       float* colsum, float* colsumsq) {
  int f = threadIdx.x & (CC - 1);
  int rl = threadIdx.x / CC;
  int r0 = blockIdx.x * 128;
  int r1 = min(NN, r0 + 128);
  float s1 = 0.f, s2 = 0.f;
  for (int r = r0 + rl; r < r1; r += 4) {
    float v = xin[(size_t)r * CC + f];
    s1 += v; s2 += v * v;
  }
  atomicAdd(&colsum[f], s1);
  atomicAdd(&colsumsq[f], s2);
}

// ---------- MLP 64->32->16->2 with fused GraphNorm+LeakyReLU on input ----------
__global__ __launch_bounds__(256) void mlp_kernel(const float* __restrict__ xin,
                                                  const float* __restrict__ colsum,
                                                  const float* __restrict__ colsumsq,
                                                  const float* __restrict__ ga,
                                                  const float* __restrict__ gw,
                                                  const float* __restrict__ gb,
                                                  const float* mW0, const float* mb0,
                                                  const float* mW1, const float* mb1,
                                                  const float* mW2, const float* mb2,
                                                  float* __restrict__ out) {
  __shared__ float W0s[64 * 32];
  __shared__ float W1s[32 * 16];
  __shared__ float W2s[16 * 2];
  __shared__ float b0s[32], b1s[16], b2s[2];
  __shared__ float sc[CC], sh[CC];
  int t = threadIdx.x;
  for (int i = t; i < 2048; i += 256) W0s[i] = mW0[i];
  for (int i = t; i < 512; i += 256) W1s[i] = mW1[i];
  if (t < 32) { W2s[t] = mW2[t]; b0s[t] = mb0[t]; }
  if (t < 16) b1s[t] = mb1[t];
  if (t < 2) b2s[t] = mb2[t];
  if (t < CC) {
    const float invn = 1.0f / (float)NN;
    float mu = colsum[t] * invn;
    float ex2 = colsumsq[t] * invn;
    float a = ga[t];
    float var = fmaxf(ex2 - (2.f * a - a * a) * mu * mu, 0.f);
    float s = gw[t] * rsqrtf(var + 1e-5f);
    sc[t] = s; sh[t] = gb[t] - s * a * mu;
  }
  __syncthreads();
  int node = blockIdx.x * 256 + t;
  if (node >= NN) return;
  float in[64];
  const float* xr = xin + (size_t)node * 64;
#pragma unroll
  for (int k = 0; k < 64; k++) {
    float y = sc[k] * xr[k] + sh[k];
    in[k] = (y > 0.f) ? y : 0.01f * y;   // GraphNorm + LeakyReLU(0.01) fused
  }
  float h1[32];
#pragma unroll
  for (int j = 0; j < 32; j++) h1[j] = b0s[j];
#pragma unroll
  for (int k = 0; k < 64; k++) {
    float v = in[k];
#pragma unroll
    for (int j = 0; j < 32; j++) h1[j] += v * W0s[k * 32 + j];
  }
#pragma unroll
  for (int j = 0; j < 32; j++) h1[j] = fmaxf(h1[j], 0.f);
  float h2[16];
#pragma unroll
  for (int j = 0; j < 16; j++) h2[j] = b1s[j];
#pragma unroll
  for (int k = 0; k < 32; k++) {
    float v = h1[k];
#pragma unroll
    for (int j = 0; j < 16; j++) h2[j] += v * W1s[k * 16 + j];
  }
#pragma unroll
  for (int j = 0; j < 16; j++) h2[j] = fmaxf(h2[j], 0.f);
  float o0 = b2s[0], o1 = b2s[1];
#pragma unroll
  for (int k = 0; k < 16; k++) {
    o0 += h2[k] * W2s[k * 2 + 0];
    o1 += h2[k] * W2s[k * 2 + 1];
  }
  out[(size_t)node * 2 + 0] = o0;
  out[(size_t)node * 2 + 1] = o1;
}

extern "C" void kernel_launch(void* const* d_in, const int* in_sizes, int n_in,
                              void* d_out, int out_size, void* d_ws, size_t ws_size,
                              hipStream_t stream) {
  const float* x = (const float*)d_in[0];
  const void* ei = d_in[1];
  const float* W[3]   = {(const float*)d_in[2],  (const float*)d_in[9],  (const float*)d_in[16]};
  const float* as_[3] = {(const float*)d_in[3],  (const float*)d_in[10], (const float*)d_in[17]};
  const float* ad_[3] = {(const float*)d_in[4],  (const float*)d_in[11], (const float*)d_in[18]};
  const float* b_[3]  = {(const float*)d_in[5],  (const float*)d_in[12], (const float*)d_in[19]};
  const float* gw[3]  = {(const float*)d_in[6],  (const float*)d_in[13], (const float*)d_in[20]};
  const float* gb[3]  = {(const float*)d_in[7],  (const float*)d_in[14], (const float*)d_in[21]};
  const float* ga[3]  = {(const float*)d_in[8],  (const float*)d_in[15], (const float*)d_in[22]};
  const float* mW0 = (const float*)d_in[23];
  const float* mb0 = (const float*)d_in[24];
  const float* mW1 = (const float*)d_in[25];
  const float* mb1 = (const float*)d_in[26];
  const float* mW2 = (const float*)d_in[27];
  const float* mb2 = (const float*)d_in[28];
  float* out = (float*)d_out;

  char* ws = (char*)d_ws;
  size_t off = 0;
  auto take = [&](size_t bytes) -> char* {
    char* p = ws + off;
    off = (off + bytes + 255) & ~(size_t)255;
    return p;
  };
  ushort* hb    = (ushort*)take((size_t)NN * FDIM * 2);
  ushort* aggb  = (ushort*)take((size_t)NN * FDIM * 2);
  float* bufD   = (float*)take((size_t)NN * CC * 4);
  ushort* Wt[3];
  for (int i = 0; i < 3; i++) Wt[i] = (ushort*)take((size_t)256 * 256 * 2);
  float* s_arr  = (float*)take((size_t)NN * HH * 4);
  float* d_arr  = (float*)take((size_t)NN * HH * 4);
  // zero-region: deg + 3 per-layer stat buffers (colsum|colsumsq each) -> ONE memset
  char* zbase   = (char*)take(0);
  int* deg      = (int*)take((size_t)NN * 4);
  float* cs[3];
  for (int i = 0; i < 3; i++) cs[i] = (float*)take(2048);   // [0:256)=colsum, [256:512)=colsumsq
  size_t zlen   = (size_t)(((char*)cs[2] + 2048) - zbase);
  int* cursor   = (int*)take((size_t)NN * 4);
  int* rowptr   = (int*)take((size_t)(NN + 1) * 4);
  int* csr_src  = (int*)take((size_t)ET * 4);
  int* bsum     = (int*)take(512);
  int* boff     = (int*)take(512);
  int* flag     = (int*)take(256);

  hipMemsetAsync(zbase, 0, zlen, stream);   // deg + all 3 layers' norm stats

  // CSR build (reused by all 3 layers)
  detect_kernel<<<1, 256, 0, stream>>>((const unsigned int*)ei, flag);
  degree_kernel<<<(ET + 255) / 256, 256, 0, stream>>>(ei, flag, deg);
  scan1_kernel<<<SCAN_NB, SCAN_BLK, 0, stream>>>(deg, rowptr, bsum);
  scan2_kernel<<<1, 128, 0, stream>>>(bsum, boff, rowptr);
  scan3_kernel<<<SCAN_NB, SCAN_BLK, 0, stream>>>(rowptr, cursor, boff);
  fill_kernel<<<(ET + 255) / 256, 256, 0, stream>>>(ei, flag, cursor, csr_src);

  // weight prep (x is consumed in f32 directly by layer-0 gemm)
  conv_w_kernel<<<dim3(256, 3), 256, 0, stream>>>(W[0], W[1], W[2], Wt[0], Wt[1], Wt[2]);

  dim3 ggrid((NN + 63) / 64, 2);
  for (int L = 0; L < 3; L++) {
    if (L == 0)
      gemm_bf16<0><<<ggrid, 256, 0, stream>>>((const void*)x, Wt[0], hb,
                                              as_[0], ad_[0], s_arr, d_arr,
                                              nullptr, nullptr, nullptr, nullptr, nullptr);
    else
      gemm_bf16<1><<<ggrid, 256, 0, stream>>>((const void*)aggb, Wt[L], hb,
                                              as_[L], ad_[L], s_arr, d_arr,
                                              cs[L - 1], cs[L - 1] + 256,
                                              ga[L - 1], gw[L - 1], gb[L - 1]);
    if (L < 2) {
      agg_kernel<true><<<NN / 4, 256, 0, stream>>>(hb, s_arr, d_arr, rowptr, csr_src, b_[L], aggb);
      norm_reduce_bf<<<(NN + 127) / 128, 256, 0, stream>>>(aggb, cs[L], cs[L] + 256);
    } else {
      agg_kernel<false><<<NN / 4, 256, 0, stream>>>(hb, s_arr, d_arr, rowptr, csr_src, b_[L], bufD);
      norm_reduce_f32<<<(NN + 127) / 128, 256, 0, stream>>>(bufD, cs[2], cs[2] + 256);
    }
  }
  mlp_kernel<<<(NN + 255) / 256, 256, 0, stream>>>(bufD, cs[2], cs[2] + 256,
                                                   ga[2], gw[2], gb[2],
                                                   mW0, mb0, mW1, mb1, mW2, mb2, out);
}